// Round 6
// baseline (609.443 us; speedup 1.0000x reference)
//
#include <hip/hip_runtime.h>
#include <hip/hip_fp16.h>

// Problem constants
#define BSZ 32
#define CS_ 640
#define CT_ 768
#define NTOK 576
#define HID 64
#define ITERS 50
#define WGB 16           // workgroups per batch
#define ROWS 36          // rows of M per workgroup (576/16)
#define NWG (BSZ*WGB)    // 512 wgs = exactly 2 per CU (uniform), 32 waves/CU
#define MPITCH 640       // halves per Ms/E row (576 real + 64 pad)
#define XPITCH 68        // halves per staged x row

#define LOG2_N 9.169925001442312f         // log2(576)
#define INV_N 0.001736111111111111f       // 1/576
#define MS_SCALE 14.426950408889634f      // 10 * log2(e):  Ms' = M/reg * log2(e)
#define M_FROM_MSP 0.06931471805599453f   // ln2 / 10

// Workspace layout (bytes)
#define OFF_CNT 0              // 32 flag groups, 64B apart (2048 B): flags[b][part]
#define OFF_DONE 2048          // int
#define OFF_GSUM 2056          // float
#define OFF_DUMMY 2112         // 512 f32 (keep-alive sink)
#define OFF_SQS 4160           // sumsq [2][32][64] f32 (16384 B)
#define OFF_PACC 20544         // col-sum accumulators [2][32][576] f32 = 147456 B
#define MEMSET_BYTES 168000
#define OFF_XS 168000          // xs fp16 [32][576][64] = 2,359,296
#define OFF_XT 2527296         // xt fp16 [32][576][64] = 2,359,296 (end 4,886,592)

// k4 LDS layout (bytes); total 61,344 -> 2 wgs/CU (122,688 <= 163,840)
#define L_MS 0                 // 36*640*2 = 46080  (Ms during build, E = 2^(Ms-mrow) during iters)
#define L_U 46080              // 36*4 = 144  (log2-domain u', needed for final)
#define L_V 46224              // 640*4 = 2560 (ew_v = 2^v during iters; log-v in final)
#define L_RED 48784            // 16*4 = 64
#define L_EU 48848             // 36*4 = 144  (eu = 2^u')
#define L_MROW 48992           // 36*4 = 144  (per-row max of Ms, for final M recovery)
#define L_UNION 49136          // iters: vtmp 576*2*4 = 4608
                               // build: ssc(256)+stc(256)+sqs(144)+sqt(2304)+xs_l(4896)+xt_l(4352)
#define SMEM_BYTES 61344

// ---------------------------------------------------------------------------
// K1 (unchanged, proven): MFMA-f16 projection GEMM.
// ---------------------------------------------------------------------------
typedef _Float16 half8 __attribute__((ext_vector_type(8)));
typedef float f32x4 __attribute__((ext_vector_type(4)));

#define APITCH 40   // halves per staged row (32 + 8 pad): 80B row -> 16B aligned

template <int C>
__device__ __forceinline__ void proj_mfma(
    const float* __restrict__ feat,   // [C][576] this batch
    const float* __restrict__ W,      // [64][C]
    const float* __restrict__ bias,   // [64]
    __half* __restrict__ out,         // [576][64] this batch
    float* __restrict__ sq,           // [64] this (side,batch)
    _Float16* lA, _Float16* lB, int nblk)
{
    const int tid = threadIdx.x;      // 256
    const int lane = tid & 63;
    const int wv = tid >> 6;          // 0..3
    const int n0 = nblk * 64;
    const int fr = lane & 15;         // fragment row/col index
    const int kg = lane >> 4;         // 0..3 -> k0 = kg*8

    f32x4 acc[4];
#pragma unroll
    for (int n = 0; n < 4; n++) acc[n] = (f32x4){0.f, 0.f, 0.f, 0.f};

    for (int c0 = 0; c0 < C; c0 += 32) {
        __syncthreads();   // protect LDS reuse from previous step's reads
#pragma unroll
        for (int q = 0; q < 8; q++) {
            int idx = tid + q * 256;          // 0..2047
            int t = idx & 63, c = idx >> 6;   // 64 t x 32 c
            lA[t * APITCH + c] = (_Float16)feat[(size_t)(c0 + c) * NTOK + n0 + t];
        }
#pragma unroll
        for (int q = 0; q < 8; q++) {
            int idx = tid + q * 256;
            int c = idx & 31, h = idx >> 5;   // 64 h x 32 c
            lB[h * APITCH + c] = (_Float16)W[(size_t)h * C + c0 + c];
        }
        __syncthreads();
        half8 a = *(const half8*)&lA[(wv * 16 + fr) * APITCH + kg * 8];
#pragma unroll
        for (int n = 0; n < 4; n++) {
            half8 b = *(const half8*)&lB[(n * 16 + fr) * APITCH + kg * 8];
            acc[n] = __builtin_amdgcn_mfma_f32_16x16x32_f16(a, b, acc[n], 0, 0, 0);
        }
    }

    // Epilogue: D: col=lane&15 -> h, row=(lane>>4)*4+reg -> tok offset.
#pragma unroll
    for (int n = 0; n < 4; n++) {
        const int h = n * 16 + fr;
        const float bv = bias[h];
        float s = 0.f;
#pragma unroll
        for (int reg = 0; reg < 4; reg++) {
            const int tok = wv * 16 + kg * 4 + reg;
            float val = acc[n][reg] + bv;
            out[(size_t)(n0 + tok) * HID + h] = __float2half(val);
            s = fmaf(val, val, s);
        }
        s += __shfl_xor(s, 16, 64);
        s += __shfl_xor(s, 32, 64);
        if (lane < 16) atomicAdd(sq + h, s);
    }
}

__global__ __launch_bounds__(256, 4) void k1_proj(
    const float* __restrict__ feat_s, const float* __restrict__ feat_t,
    const float* __restrict__ Ws, const float* __restrict__ bs,
    const float* __restrict__ Wt, const float* __restrict__ bt,
    __half* __restrict__ xs, __half* __restrict__ xt, float* __restrict__ sumsq)
{
    __shared__ __align__(16) _Float16 lA[64 * APITCH];
    __shared__ __align__(16) _Float16 lB[64 * APITCH];
    const int nblk = blockIdx.x, b = blockIdx.y, st = blockIdx.z;
    if (st == 0) {
        proj_mfma<CS_>(feat_s + (size_t)b * CS_ * NTOK, Ws, bs,
                       xs + (size_t)b * NTOK * HID, sumsq + b * 64, lA, lB, nblk);
    } else {
        proj_mfma<CT_>(feat_t + (size_t)b * CT_ * NTOK, Wt, bt,
                       xt + (size_t)b * NTOK * HID, sumsq + (BSZ + b) * 64, lA, lB, nblk);
    }
}

// ---------------------------------------------------------------------------
// K4: persistent Sinkhorn — EXACT round-5 structure (flags protocol, 357 us),
// ONE change: anti-phase co-residency. blockIdx remap
//   b = (w&7) | ((w>>7)<<3), part = (w>>3)&15
// keeps each batch's 16 parts on one XCD class (w%8 == b&7, same as before)
// but makes the round-robin co-resident pair (w, w+256) serve DIFFERENT
// batches (b, b+16). Batches 16..31 start the iteration loop ~8K cycles
// (~half an iteration) late, so on every CU one WG computes while the other
// waits in the flag exchange -> compute runs at full SIMD rate and the
// exchange latency is hidden behind the partner's compute.
// ---------------------------------------------------------------------------
__global__ __launch_bounds__(1024, 8) void k4_sinkhorn(
    const __half* __restrict__ xsh, const __half* __restrict__ xth,
    const float* __restrict__ sumsq, float* __restrict__ Pacc,
    int* __restrict__ counters, int* __restrict__ done,
    float* __restrict__ gsum, float* __restrict__ dummyout,
    float* __restrict__ out)
{
    extern __shared__ char smem[];
    __half* Ms  = (__half*)(smem + L_MS);          // Ms during build, E during iters
    float* u_l  = (float*)(smem + L_U);
    float* ewv  = (float*)(smem + L_V);            // ew_v during iters; log-v in final
    float* red  = (float*)(smem + L_RED);
    float* eu_l = (float*)(smem + L_EU);
    float* mrow = (float*)(smem + L_MROW);
    float* vtmp = (float*)(smem + L_UNION);
    float* ssc  = (float*)(smem + L_UNION);
    float* stc  = (float*)(smem + L_UNION + 256);
    float* sqs  = (float*)(smem + L_UNION + 512);
    float* sqt  = (float*)(smem + L_UNION + 656);
    __half* xs_l = (__half*)(smem + L_UNION + 2960);
    __half* xt_l = (__half*)(smem + L_UNION + 7856);

    const int tid = threadIdx.x;
    const int w = blockIdx.x;
    const int b = (w & 7) | ((w >> 7) << 3);   // batch; all its parts share w%8 (XCD class)
    const int part = (w >> 3) & 15;
    const int r0 = part * ROWS;
    const int lane = tid & 63, wv = tid >> 6;
    float dummy = 0.f;
    float s_kept = 0.f;

    if (tid < 64) {
        ssc[tid] = 1.0f / fmaxf(sqrtf(sumsq[b * 64 + tid]), 1e-12f);
    } else if (tid < 128) {
        stc[tid - 64] = 1.0f / fmaxf(sqrtf(sumsq[BSZ * 64 + b * 64 + (tid - 64)]), 1e-12f);
    }
    // ew_v = 2^v; v starts at 0 -> 1.0 (pad columns: 0 so they contribute nothing)
    for (int m = tid; m < MPITCH; m += 1024) ewv[m] = (m < NTOK) ? 1.0f : 0.f;
    __syncthreads();

    for (int idx = tid; idx < ROWS * 64; idx += 1024) {
        int r = idx >> 6, h = idx & 63;
        xs_l[r * XPITCH + h] =
            __float2half(__half2float(xsh[((size_t)b * NTOK + r0 + r) * 64 + h]) * ssc[h]);
    }
    if (tid < NTOK) {
        const __half* tp = xth + ((size_t)b * NTOK + tid) * 64;
        float s = 0.f;
#pragma unroll
        for (int h = 0; h < 64; h++) { float v = __half2float(tp[h]) * stc[h]; s = fmaf(v, v, s); }
        sqt[tid] = s;
    }
    __syncthreads();
    if (tid < ROWS) {
        float s = 0.f;
#pragma unroll
        for (int h = 0; h < 64; h++) { float v = __half2float(xs_l[tid * XPITCH + h]); s = fmaf(v, v, s); }
        sqs[tid] = s;
    }

    for (int c0 = 0; c0 < NTOK; c0 += 32) {
        __syncthreads();
        for (int idx = tid; idx < 32 * 64; idx += 1024) {
            int m = idx >> 6, h = idx & 63;
            xt_l[m * XPITCH + h] =
                __float2half(__half2float(xth[((size_t)b * NTOK + c0 + m) * 64 + h]) * stc[h]);
        }
        __syncthreads();
        for (int idx = tid; idx < ROWS * 32; idx += 1024) {
            int r = idx >> 5, c = idx & 31;
            const __half2* xr = (const __half2*)(xs_l + r * XPITCH);
            const __half2* tr = (const __half2*)(xt_l + c * XPITCH);
            float d = 0.f;
#pragma unroll
            for (int h2 = 0; h2 < 32; h2++) {
                float2 av = __half22float2(xr[h2]);
                float2 tv = __half22float2(tr[h2]);
                d = fmaf(av.x, tv.x, d);
                d = fmaf(av.y, tv.y, d);
            }
            float M = fmaxf(sqs[r] + sqt[c] - 2.f * d, 0.f);
            Ms[r * MPITCH + c0 + c] = __float2half(M * MS_SCALE);
        }
    }
    __syncthreads();
    for (int idx = tid; idx < ROWS * (MPITCH - NTOK); idx += 1024) {
        int r = idx >> 6, k = idx & 63;
        Ms[r * MPITCH + NTOK + k] = __float2half(-1000.f);
    }
    __syncthreads();

    // ---- One-time transform: Ms -> E = 2^(Ms - rowmax), record rowmax.
    // Per-row max self-cancels through the u/v algebra, so Pacc column sums
    // are identical to the untransformed computation. Pad entries -> 0.
    for (int r = wv; r < ROWS; r += 16) {
        __half* row = Ms + r * MPITCH;
        float2 f[5];
        float mx = 0.f;   // real Ms >= 0, pad = -1000 never wins
#pragma unroll
        for (int j = 0; j < 5; j++) {
            f[j] = __half22float2(*(const __half2*)&row[128 * j + 2 * lane]);
            mx = fmaxf(mx, fmaxf(f[j].x, f[j].y));
        }
#pragma unroll
        for (int off = 32; off > 0; off >>= 1) mx = fmaxf(mx, __shfl_xor(mx, off, 64));
        if (lane == 0) mrow[r] = mx;
#pragma unroll
        for (int j = 0; j < 5; j++) {
            *(__half2*)&row[128 * j + 2 * lane] = __floats2half2_rn(
                __builtin_amdgcn_exp2f(f[j].x - mx), __builtin_amdgcn_exp2f(f[j].y - mx));
        }
    }
    __syncthreads();

    // ---- Anti-phase stagger: the co-resident partner WG (w^256) serves
    // batch b^16; delay the upper half by ~half an iteration so one WG's
    // exchange stall overlaps the other's compute. Timing-only: correctness
    // does not depend on dispatch placement.
    if (w >> 8) {
        for (int i = 0; i < 64; ++i) __builtin_amdgcn_s_sleep(2);   // ~8K cycles
    }

    int* flags = counters + b * 16;   // 16 write-once flags, one 64B line per batch

    for (int it = 1; it <= ITERS; ++it) {
        if (it > 1) {
            if (tid < NTOK) {
                const int qr = (it - 1) & 1, qw = it & 1;
                float s = __hip_atomic_load(&Pacc[(size_t)(qr * BSZ + b) * NTOK + tid],
                                            __ATOMIC_RELAXED, __HIP_MEMORY_SCOPE_AGENT);
                ewv[tid] = INV_N * __builtin_amdgcn_rcpf(s);   // 2^v = (1/N)/colsum
                if (tid >= r0 && tid < r0 + ROWS) {
                    if (s_kept != 0.f)
                        dummy += __hip_atomic_fetch_add(
                            &Pacc[(size_t)(qw * BSZ + b) * NTOK + tid], -s_kept,
                            __ATOMIC_RELAXED, __HIP_MEMORY_SCOPE_AGENT);
                    s_kept = s;
                }
            }
            __syncthreads();
        }
        // ---- Row pass: rowsum_r = sum_c E_rc * ew_v_c  (pure cvt+fma)
        float2 vr[5];
#pragma unroll
        for (int j = 0; j < 5; j++) vr[j] = *(const float2*)&ewv[128 * j + 2 * lane];
        for (int r = wv; r < ROWS; r += 16) {
            const __half* row = Ms + r * MPITCH;
            float a = 0.f;
#pragma unroll
            for (int j = 0; j < 5; j++) {
                float2 f = __half22float2(*(const __half2*)&row[128 * j + 2 * lane]);
                a = fmaf(f.x, vr[j].x, a);
                a = fmaf(f.y, vr[j].y, a);
            }
#pragma unroll
            for (int off = 32; off > 0; off >>= 1) a += __shfl_xor(a, off, 64);
            if (lane == 0) {
                eu_l[r] = INV_N * __builtin_amdgcn_rcpf(a);    // 2^u' = (1/N)/rowsum
                u_l[r] = -LOG2_N - __builtin_amdgcn_logf(a);   // log2-domain u' for final
            }
        }
        __syncthreads();
        // ---- Col pass: partial colsum_c = sum_r E_rc * eu_r  (pure cvt+fma)
        if (tid < NTOK) {
            int hf = tid / 288, p = tid - hf * 288;
            const __half* col = Ms + 2 * p;
            float a0 = 0.f, a1 = 0.f;
            int n1 = hf * 18;
#pragma unroll
            for (int nn = 0; nn < 18; nn++, n1++) {
                float uu = eu_l[n1];
                float2 f = __half22float2(*(const __half2*)&col[n1 * MPITCH]);
                a0 = fmaf(f.x, uu, a0);
                a1 = fmaf(f.y, uu, a1);
            }
            ((float2*)vtmp)[hf * 288 + p] = make_float2(a0, a1);
        }
        __syncthreads();
        if (tid < NTOK) {
            float s = vtmp[tid] + vtmp[NTOK + tid];
            dummy += __hip_atomic_fetch_add(&Pacc[(size_t)((it & 1) * BSZ + b) * NTOK + tid], s,
                                            __ATOMIC_RELAXED, __HIP_MEMORY_SCOPE_AGENT);
        }
        __syncthreads();   // drains publishes (vmcnt(0) before s_barrier)
        if (tid < WGB) {
            if (tid == part)
                __hip_atomic_store(&flags[tid], it, __ATOMIC_RELAXED, __HIP_MEMORY_SCOPE_AGENT);
            while (__hip_atomic_load(&flags[tid], __ATOMIC_RELAXED, __HIP_MEMORY_SCOPE_AGENT) < it)
                __builtin_amdgcn_s_sleep(1);
        }
        __syncthreads();
    }

    // ---- Final: v (log2 domain) from Pacc; T*M with M = (log2(E) + rowmax) * ln2/10
    float* v_log = ewv;   // reuse buffer
    if (tid < NTOK) {
        float s = __hip_atomic_load(&Pacc[(size_t)b * NTOK + tid],
                                    __ATOMIC_RELAXED, __HIP_MEMORY_SCOPE_AGENT);
        v_log[tid] = -LOG2_N - __builtin_amdgcn_logf(s);
    }
    __syncthreads();
    float acc = 0.f;
    for (int idx = tid; idx < ROWS * NTOK; idx += 1024) {
        int r = idx / NTOK, m = idx - r * NTOK;
        float e = __half2float(Ms[r * MPITCH + m]);
        if (e > 0.f) {
            float msp = __builtin_amdgcn_logf(e) + mrow[r];
            acc = fmaf(__builtin_amdgcn_exp2f(u_l[r] + v_log[m]) * e, msp, acc);
        }
    }
#pragma unroll
    for (int off = 32; off > 0; off >>= 1) acc += __shfl_xor(acc, off, 64);
    if (lane == 0) red[wv] = acc;
    __syncthreads();
    if (tid == 0) {
        float s = 0.f;
#pragma unroll
        for (int w2 = 0; w2 < 16; w2++) s += red[w2];
        float old = __hip_atomic_fetch_add(gsum, s * M_FROM_MSP,
                                           __ATOMIC_RELAXED, __HIP_MEMORY_SCOPE_AGENT);
        int* dptr = done + ((old == -1.2345678e33f) ? 1 : 0);
        int prev = __hip_atomic_fetch_add(dptr, 1, __ATOMIC_RELAXED, __HIP_MEMORY_SCOPE_AGENT);
        if (prev == NWG - 1) {
            float tot = __hip_atomic_load(gsum, __ATOMIC_RELAXED, __HIP_MEMORY_SCOPE_AGENT);
            out[0] = tot * (1.0f / BSZ);
        }
    }
    if (dummy == -1.2345678e33f) dummyout[blockIdx.x] = 1.f;
}

extern "C" void kernel_launch(void* const* d_in, const int* in_sizes, int n_in,
                              void* d_out, int out_size, void* d_ws, size_t ws_size,
                              hipStream_t stream) {
    const float* feat_s = (const float*)d_in[0];
    const float* feat_t = (const float*)d_in[1];
    const float* Ws = (const float*)d_in[2];
    const float* bs = (const float*)d_in[3];
    const float* Wt = (const float*)d_in[4];
    const float* bt = (const float*)d_in[5];

    char* ws = (char*)d_ws;
    int* counters  = (int*)(ws + OFF_CNT);
    int* done      = (int*)(ws + OFF_DONE);
    float* gsum    = (float*)(ws + OFF_GSUM);
    float* dummyo  = (float*)(ws + OFF_DUMMY);
    float* sumsq   = (float*)(ws + OFF_SQS);
    float* Pacc    = (float*)(ws + OFF_PACC);
    __half* xs     = (__half*)(ws + OFF_XS);
    __half* xt     = (__half*)(ws + OFF_XT);
    float* out = (float*)d_out;

    hipMemsetAsync(ws, 0, MEMSET_BYTES, stream);

    hipLaunchKernelGGL(k1_proj, dim3(9, 32, 2), dim3(256), 0, stream,
                       feat_s, feat_t, Ws, bs, Wt, bt, xs, xt, sumsq);

    (void)hipFuncSetAttribute((const void*)k4_sinkhorn,
                              hipFuncAttributeMaxDynamicSharedMemorySize, SMEM_BYTES);
    hipLaunchKernelGGL(k4_sinkhorn, dim3(NWG), dim3(1024), SMEM_BYTES, stream,
                       xs, xt, sumsq, Pacc, counters, done, gsum, dummyo, out);
}

// Round 7
// 557.871 us; speedup vs baseline: 1.0924x; 1.0924x over previous
//
#include <hip/hip_runtime.h>
#include <hip/hip_fp16.h>

// Problem constants
#define BSZ 32
#define CS_ 640
#define CT_ 768
#define NTOK 576
#define HID 64
#define ITERS 50
#define WGB 16           // workgroups per batch
#define ROWS 36          // rows of M per workgroup (576/16)
#define NWG (BSZ*WGB)    // 512 wgs = exactly 2 per CU (uniform), 32 waves/CU
#define MPITCH 640       // halves per Ms/E row (576 real + 64 pad)
#define XPITCH 68        // halves per staged x row

#define LOG2_N 9.169925001442312f         // log2(576)
#define INV_N 0.001736111111111111f       // 1/576
#define MS_SCALE 14.426950408889634f      // 10 * log2(e):  Ms' = M/reg * log2(e)
#define M_FROM_MSP 0.06931471805599453f   // ln2 / 10

// Workspace layout (bytes)
#define OFF_CNT 0              // 32 flag groups, 64B apart (2048 B): flags[b][part]
#define OFF_DONE 2048          // int
#define OFF_GSUM 2056          // float
#define OFF_DUMMY 2112         // 512 f32 (keep-alive sink)
#define OFF_SQS 4160           // sumsq [2][32][64] f32 (16384 B)
#define OFF_PACC 20544         // col-sum accumulators [2][32][576] f32 = 147456 B
#define MEMSET_BYTES 168000
#define OFF_XS 168000          // xs fp16 [32][576][64] = 2,359,296
#define OFF_XT 2527296         // xt fp16 [32][576][64] = 2,359,296 (end 4,886,592)

// k4 LDS layout (bytes); total 62,576 -> 2 wgs/CU (125,152 <= 163,840)
#define L_MS 0                 // 36*640*2 = 46080  (Ms during build, E during iters)
#define L_U 46080              // 36*4 = 144  (log2-domain u', for final)
#define L_V 46224              // 640*4 = 2560 (fp32; used only for final v_log)
#define L_RED 48784            // 16*4 = 64
#define L_EUH 48848            // 40 halves (eu as fp16 per row, pairs 4B-aligned) pad 96
#define L_MROW 48944           // 36*4 = 144 (per-row max of Ms, for final M recovery)
#define L_EWH 49088            // 640 halves = 1280 (ew_v = 2^v as fp16; pad cols 0)
#define L_UNION 50368          // iters: vtmp 3*576*4 = 6912
                               // build: ssc(256)+stc(256)+sqs(144)+sqt(2304)+xs_l(4896)+xt_l(4352)
#define SMEM_BYTES 62576

typedef _Float16 half8 __attribute__((ext_vector_type(8)));
typedef _Float16 h2f __attribute__((ext_vector_type(2)));
typedef float f32x4 __attribute__((ext_vector_type(4)));

#if defined(__has_builtin)
#if __has_builtin(__builtin_amdgcn_fdot2)
#define HAVE_FDOT2 1
#endif
#endif

__device__ __forceinline__ float fdot2f(h2f a, h2f b, float c) {
#ifdef HAVE_FDOT2
    return __builtin_amdgcn_fdot2(a, b, c, false);
#else
    return fmaf((float)a[0], (float)b[0], fmaf((float)a[1], (float)b[1], c));
#endif
}

// ---------------------------------------------------------------------------
// K1 (unchanged, proven): MFMA-f16 projection GEMM.
// ---------------------------------------------------------------------------
#define APITCH 40   // halves per staged row (32 + 8 pad): 80B row -> 16B aligned

template <int C>
__device__ __forceinline__ void proj_mfma(
    const float* __restrict__ feat,   // [C][576] this batch
    const float* __restrict__ W,      // [64][C]
    const float* __restrict__ bias,   // [64]
    __half* __restrict__ out,         // [576][64] this batch
    float* __restrict__ sq,           // [64] this (side,batch)
    _Float16* lA, _Float16* lB, int nblk)
{
    const int tid = threadIdx.x;      // 256
    const int lane = tid & 63;
    const int wv = tid >> 6;          // 0..3
    const int n0 = nblk * 64;
    const int fr = lane & 15;         // fragment row/col index
    const int kg = lane >> 4;         // 0..3 -> k0 = kg*8

    f32x4 acc[4];
#pragma unroll
    for (int n = 0; n < 4; n++) acc[n] = (f32x4){0.f, 0.f, 0.f, 0.f};

    for (int c0 = 0; c0 < C; c0 += 32) {
        __syncthreads();   // protect LDS reuse from previous step's reads
#pragma unroll
        for (int q = 0; q < 8; q++) {
            int idx = tid + q * 256;          // 0..2047
            int t = idx & 63, c = idx >> 6;   // 64 t x 32 c
            lA[t * APITCH + c] = (_Float16)feat[(size_t)(c0 + c) * NTOK + n0 + t];
        }
#pragma unroll
        for (int q = 0; q < 8; q++) {
            int idx = tid + q * 256;
            int c = idx & 31, h = idx >> 5;   // 64 h x 32 c
            lB[h * APITCH + c] = (_Float16)W[(size_t)h * C + c0 + c];
        }
        __syncthreads();
        half8 a = *(const half8*)&lA[(wv * 16 + fr) * APITCH + kg * 8];
#pragma unroll
        for (int n = 0; n < 4; n++) {
            half8 b = *(const half8*)&lB[(n * 16 + fr) * APITCH + kg * 8];
            acc[n] = __builtin_amdgcn_mfma_f32_16x16x32_f16(a, b, acc[n], 0, 0, 0);
        }
    }

    // Epilogue: D: col=lane&15 -> h, row=(lane>>4)*4+reg -> tok offset.
#pragma unroll
    for (int n = 0; n < 4; n++) {
        const int h = n * 16 + fr;
        const float bv = bias[h];
        float s = 0.f;
#pragma unroll
        for (int reg = 0; reg < 4; reg++) {
            const int tok = wv * 16 + kg * 4 + reg;
            float val = acc[n][reg] + bv;
            out[(size_t)(n0 + tok) * HID + h] = __float2half(val);
            s = fmaf(val, val, s);
        }
        s += __shfl_xor(s, 16, 64);
        s += __shfl_xor(s, 32, 64);
        if (lane < 16) atomicAdd(sq + h, s);
    }
}

__global__ __launch_bounds__(256, 4) void k1_proj(
    const float* __restrict__ feat_s, const float* __restrict__ feat_t,
    const float* __restrict__ Ws, const float* __restrict__ bs,
    const float* __restrict__ Wt, const float* __restrict__ bt,
    __half* __restrict__ xs, __half* __restrict__ xt, float* __restrict__ sumsq)
{
    __shared__ __align__(16) _Float16 lA[64 * APITCH];
    __shared__ __align__(16) _Float16 lB[64 * APITCH];
    const int nblk = blockIdx.x, b = blockIdx.y, st = blockIdx.z;
    if (st == 0) {
        proj_mfma<CS_>(feat_s + (size_t)b * CS_ * NTOK, Ws, bs,
                       xs + (size_t)b * NTOK * HID, sumsq + b * 64, lA, lB, nblk);
    } else {
        proj_mfma<CT_>(feat_t + (size_t)b * CT_ * NTOK, Wt, bt,
                       xt + (size_t)b * NTOK * HID, sumsq + (BSZ + b) * 64, lA, lB, nblk);
    }
}

// ---------------------------------------------------------------------------
// K4: persistent Sinkhorn — EXACT round-5 exchange protocol (flags, 357 us):
// blockIdx b=w&31 / part=w>>5, fence-free double-buffered Pacc + re-poison.
// VALU cut in the hot passes:
//  - row pass: E(half2) x ewv(half2) via v_dot2_f32_f16 (fp32 accumulate)
//  - col pass: row-paired fdot2 — v_perm_b32 repacks (Ax,Bx)/(Ay,By) from two
//    row loads, dotted with the (eu[n1],eu[n1+1]) half pair; 3-way row split
//    (864 workers x 12 rows) instead of 2-way (576 x 18).
// Potentials applied in fp16; all exchanged values (Pacc, vtmp, final u/v)
// remain fp32, so cross-iteration marginals keep full precision.
// ---------------------------------------------------------------------------
__global__ __launch_bounds__(1024, 8) void k4_sinkhorn(
    const __half* __restrict__ xsh, const __half* __restrict__ xth,
    const float* __restrict__ sumsq, float* __restrict__ Pacc,
    int* __restrict__ counters, int* __restrict__ done,
    float* __restrict__ gsum, float* __restrict__ dummyout,
    float* __restrict__ out)
{
    extern __shared__ char smem[];
    __half* Ms  = (__half*)(smem + L_MS);          // Ms during build, E during iters
    _Float16* MsH = (_Float16*)(smem + L_MS);
    float* u_l  = (float*)(smem + L_U);
    float* vlg  = (float*)(smem + L_V);            // final-only v_log buffer
    float* red  = (float*)(smem + L_RED);
    _Float16* eu_h = (_Float16*)(smem + L_EUH);    // eu = 2^u' as fp16 per row
    float* mrow = (float*)(smem + L_MROW);
    _Float16* ewh = (_Float16*)(smem + L_EWH);     // ew_v = 2^v as fp16 per col
    float* vtmp = (float*)(smem + L_UNION);        // [3][576] col partials
    float* ssc  = (float*)(smem + L_UNION);
    float* stc  = (float*)(smem + L_UNION + 256);
    float* sqs  = (float*)(smem + L_UNION + 512);
    float* sqt  = (float*)(smem + L_UNION + 656);
    __half* xs_l = (__half*)(smem + L_UNION + 2960);
    __half* xt_l = (__half*)(smem + L_UNION + 7856);

    const int tid = threadIdx.x;
    const int b = blockIdx.x & 31, part = blockIdx.x >> 5;
    const int r0 = part * ROWS;
    const int lane = tid & 63, wv = tid >> 6;
    float dummy = 0.f;
    float s_kept = 0.f;

    if (tid < 64) {
        ssc[tid] = 1.0f / fmaxf(sqrtf(sumsq[b * 64 + tid]), 1e-12f);
    } else if (tid < 128) {
        stc[tid - 64] = 1.0f / fmaxf(sqrtf(sumsq[BSZ * 64 + b * 64 + (tid - 64)]), 1e-12f);
    }
    // ewh = 2^v; v starts at 0 -> 1.0 (pad columns: 0 so they contribute nothing)
    for (int m = tid; m < MPITCH; m += 1024) ewh[m] = (m < NTOK) ? (_Float16)1.0f : (_Float16)0.0f;
    __syncthreads();

    for (int idx = tid; idx < ROWS * 64; idx += 1024) {
        int r = idx >> 6, h = idx & 63;
        xs_l[r * XPITCH + h] =
            __float2half(__half2float(xsh[((size_t)b * NTOK + r0 + r) * 64 + h]) * ssc[h]);
    }
    if (tid < NTOK) {
        const __half* tp = xth + ((size_t)b * NTOK + tid) * 64;
        float s = 0.f;
#pragma unroll
        for (int h = 0; h < 64; h++) { float v = __half2float(tp[h]) * stc[h]; s = fmaf(v, v, s); }
        sqt[tid] = s;
    }
    __syncthreads();
    if (tid < ROWS) {
        float s = 0.f;
#pragma unroll
        for (int h = 0; h < 64; h++) { float v = __half2float(xs_l[tid * XPITCH + h]); s = fmaf(v, v, s); }
        sqs[tid] = s;
    }

    for (int c0 = 0; c0 < NTOK; c0 += 32) {
        __syncthreads();
        for (int idx = tid; idx < 32 * 64; idx += 1024) {
            int m = idx >> 6, h = idx & 63;
            xt_l[m * XPITCH + h] =
                __float2half(__half2float(xth[((size_t)b * NTOK + c0 + m) * 64 + h]) * stc[h]);
        }
        __syncthreads();
        for (int idx = tid; idx < ROWS * 32; idx += 1024) {
            int r = idx >> 5, c = idx & 31;
            const __half2* xr = (const __half2*)(xs_l + r * XPITCH);
            const __half2* tr = (const __half2*)(xt_l + c * XPITCH);
            float d = 0.f;
#pragma unroll
            for (int h2 = 0; h2 < 32; h2++) {
                float2 av = __half22float2(xr[h2]);
                float2 tv = __half22float2(tr[h2]);
                d = fmaf(av.x, tv.x, d);
                d = fmaf(av.y, tv.y, d);
            }
            float M = fmaxf(sqs[r] + sqt[c] - 2.f * d, 0.f);
            Ms[r * MPITCH + c0 + c] = __float2half(M * MS_SCALE);
        }
    }
    __syncthreads();
    for (int idx = tid; idx < ROWS * (MPITCH - NTOK); idx += 1024) {
        int r = idx >> 6, k = idx & 63;
        Ms[r * MPITCH + NTOK + k] = __float2half(-1000.f);
    }
    __syncthreads();

    // ---- One-time transform: Ms -> E = 2^(Ms - rowmax), record rowmax.
    for (int r = wv; r < ROWS; r += 16) {
        __half* row = Ms + r * MPITCH;
        float2 f[5];
        float mx = 0.f;   // real Ms >= 0, pad = -1000 never wins
#pragma unroll
        for (int j = 0; j < 5; j++) {
            f[j] = __half22float2(*(const __half2*)&row[128 * j + 2 * lane]);
            mx = fmaxf(mx, fmaxf(f[j].x, f[j].y));
        }
#pragma unroll
        for (int off = 32; off > 0; off >>= 1) mx = fmaxf(mx, __shfl_xor(mx, off, 64));
        if (lane == 0) mrow[r] = mx;
#pragma unroll
        for (int j = 0; j < 5; j++) {
            *(__half2*)&row[128 * j + 2 * lane] = __floats2half2_rn(
                __builtin_amdgcn_exp2f(f[j].x - mx), __builtin_amdgcn_exp2f(f[j].y - mx));
        }
    }
    __syncthreads();

    int* flags = counters + b * 16;   // 16 write-once flags, one 64B line per batch

    for (int it = 1; it <= ITERS; ++it) {
        if (it > 1) {
            if (tid < NTOK) {
                const int qr = (it - 1) & 1, qw = it & 1;
                float s = __hip_atomic_load(&Pacc[(size_t)(qr * BSZ + b) * NTOK + tid],
                                            __ATOMIC_RELAXED, __HIP_MEMORY_SCOPE_AGENT);
                ewh[tid] = (_Float16)(INV_N * __builtin_amdgcn_rcpf(s));   // 2^v
                if (tid >= r0 && tid < r0 + ROWS) {
                    if (s_kept != 0.f)
                        dummy += __hip_atomic_fetch_add(
                            &Pacc[(size_t)(qw * BSZ + b) * NTOK + tid], -s_kept,
                            __ATOMIC_RELAXED, __HIP_MEMORY_SCOPE_AGENT);
                    s_kept = s;
                }
            }
            __syncthreads();
        }
        // ---- Row pass: rowsum_r = sum_c E_rc * ewv_c  (fdot2, fp32 accum)
        h2f vrh[5];
#pragma unroll
        for (int j = 0; j < 5; j++) vrh[j] = *(const h2f*)&ewh[128 * j + 2 * lane];
        for (int r = wv; r < ROWS; r += 16) {
            const _Float16* row = MsH + r * MPITCH;
            float a = 0.f;
#pragma unroll
            for (int j = 0; j < 5; j++)
                a = fdot2f(*(const h2f*)&row[128 * j + 2 * lane], vrh[j], a);
#pragma unroll
            for (int off = 32; off > 0; off >>= 1) a += __shfl_xor(a, off, 64);
            if (lane == 0) {
                eu_h[r] = (_Float16)(INV_N * __builtin_amdgcn_rcpf(a));  // 2^u'
                u_l[r] = -LOG2_N - __builtin_amdgcn_logf(a);   // log2-domain for final
            }
        }
        __syncthreads();
        // ---- Col pass: partial colsum over 12 rows per worker (864 workers),
        // row-paired fdot2 with v_perm repack.
        if (tid < 864) {
            int q = tid / 288, p = tid - q * 288;     // q: row-third, p: col pair
            const _Float16* col = MsH + 2 * p;
            float a0 = 0.f, a1 = 0.f;
            int n1 = q * 12;
#pragma unroll
            for (int nn = 0; nn < 6; nn++, n1 += 2) {
                uint ea = *(const uint*)&col[n1 * MPITCH];         // (E[n1,2p],E[n1,2p+1])
                uint eb = *(const uint*)&col[(n1 + 1) * MPITCH];   // (E[n1+1,2p],E[n1+1,2p+1])
                h2f up = *(const h2f*)&eu_h[n1];                   // (eu[n1],eu[n1+1])
                uint xpk = __builtin_amdgcn_perm(eb, ea, 0x05040100u);  // (Ax,Bx)
                uint ypk = __builtin_amdgcn_perm(eb, ea, 0x07060302u);  // (Ay,By)
                a0 = fdot2f(__builtin_bit_cast(h2f, xpk), up, a0);
                a1 = fdot2f(__builtin_bit_cast(h2f, ypk), up, a1);
            }
            ((float2*)(vtmp + q * NTOK))[p] = make_float2(a0, a1);
        }
        __syncthreads();
        if (tid < NTOK) {
            float s = vtmp[tid] + vtmp[NTOK + tid] + vtmp[2 * NTOK + tid];
            dummy += __hip_atomic_fetch_add(&Pacc[(size_t)((it & 1) * BSZ + b) * NTOK + tid], s,
                                            __ATOMIC_RELAXED, __HIP_MEMORY_SCOPE_AGENT);
        }
        __syncthreads();   // drains publishes (vmcnt(0) before s_barrier)
        if (tid < WGB) {
            if (tid == part)
                __hip_atomic_store(&flags[tid], it, __ATOMIC_RELAXED, __HIP_MEMORY_SCOPE_AGENT);
            while (__hip_atomic_load(&flags[tid], __ATOMIC_RELAXED, __HIP_MEMORY_SCOPE_AGENT) < it)
                __builtin_amdgcn_s_sleep(1);
        }
        __syncthreads();
    }

    // ---- Final: v (log2 domain) from Pacc; T*M with M = (log2(E) + rowmax) * ln2/10
    if (tid < NTOK) {
        float s = __hip_atomic_load(&Pacc[(size_t)b * NTOK + tid],
                                    __ATOMIC_RELAXED, __HIP_MEMORY_SCOPE_AGENT);
        vlg[tid] = -LOG2_N - __builtin_amdgcn_logf(s);
    }
    __syncthreads();
    float acc = 0.f;
    for (int idx = tid; idx < ROWS * NTOK; idx += 1024) {
        int r = idx / NTOK, m = idx - r * NTOK;
        float e = __half2float(Ms[r * MPITCH + m]);
        if (e > 0.f) {
            float msp = __builtin_amdgcn_logf(e) + mrow[r];
            acc = fmaf(__builtin_amdgcn_exp2f(u_l[r] + vlg[m]) * e, msp, acc);
        }
    }
#pragma unroll
    for (int off = 32; off > 0; off >>= 1) acc += __shfl_xor(acc, off, 64);
    if (lane == 0) red[wv] = acc;
    __syncthreads();
    if (tid == 0) {
        float s = 0.f;
#pragma unroll
        for (int w2 = 0; w2 < 16; w2++) s += red[w2];
        float old = __hip_atomic_fetch_add(gsum, s * M_FROM_MSP,
                                           __ATOMIC_RELAXED, __HIP_MEMORY_SCOPE_AGENT);
        int* dptr = done + ((old == -1.2345678e33f) ? 1 : 0);
        int prev = __hip_atomic_fetch_add(dptr, 1, __ATOMIC_RELAXED, __HIP_MEMORY_SCOPE_AGENT);
        if (prev == NWG - 1) {
            float tot = __hip_atomic_load(gsum, __ATOMIC_RELAXED, __HIP_MEMORY_SCOPE_AGENT);
            out[0] = tot * (1.0f / BSZ);
        }
    }
    if (dummy == -1.2345678e33f) dummyout[blockIdx.x] = 1.f;
}

extern "C" void kernel_launch(void* const* d_in, const int* in_sizes, int n_in,
                              void* d_out, int out_size, void* d_ws, size_t ws_size,
                              hipStream_t stream) {
    const float* feat_s = (const float*)d_in[0];
    const float* feat_t = (const float*)d_in[1];
    const float* Ws = (const float*)d_in[2];
    const float* bs = (const float*)d_in[3];
    const float* Wt = (const float*)d_in[4];
    const float* bt = (const float*)d_in[5];

    char* ws = (char*)d_ws;
    int* counters  = (int*)(ws + OFF_CNT);
    int* done      = (int*)(ws + OFF_DONE);
    float* gsum    = (float*)(ws + OFF_GSUM);
    float* dummyo  = (float*)(ws + OFF_DUMMY);
    float* sumsq   = (float*)(ws + OFF_SQS);
    float* Pacc    = (float*)(ws + OFF_PACC);
    __half* xs     = (__half*)(ws + OFF_XS);
    __half* xt     = (__half*)(ws + OFF_XT);
    float* out = (float*)d_out;

    hipMemsetAsync(ws, 0, MEMSET_BYTES, stream);

    hipLaunchKernelGGL(k1_proj, dim3(9, 32, 2), dim3(256), 0, stream,
                       feat_s, feat_t, Ws, bs, Wt, bt, xs, xt, sumsq);

    (void)hipFuncSetAttribute((const void*)k4_sinkhorn,
                              hipFuncAttributeMaxDynamicSharedMemorySize, SMEM_BYTES);
    hipLaunchKernelGGL(k4_sinkhorn, dim3(NWG), dim3(1024), SMEM_BYTES, stream,
                       xs, xt, sumsq, Pacc, counters, done, gsum, dummyo, out);
}